// Round 2
// baseline (338.119 us; speedup 1.0000x reference)
//
#include <hip/hip_runtime.h>

#define NBATCH 4
#define NPTS   16384
#define NQ     4096
#define NCH    64
#define K      32
#define CHOUT  67   // 3 + NCH

typedef float v2f __attribute__((ext_vector_type(2)));
typedef float v4f __attribute__((ext_vector_type(4)));
typedef int   v4i __attribute__((ext_vector_type(4)));

// Packed fp32 ops via asm: exact rn rounding, no contraction possible.
__device__ __forceinline__ v2f pk_add(v2f a, v2f b) {
    v2f d; asm("v_pk_add_f32 %0, %1, %2" : "=v"(d) : "v"(a), "v"(b)); return d;
}
__device__ __forceinline__ v2f pk_mul(v2f a, v2f b) {
    v2f d; asm("v_pk_mul_f32 %0, %1, %2" : "=v"(d) : "v"(a), "v"(b)); return d;
}
// FMA variant: used ONLY in pass 1 (threshold estimate), never for the exact
// pass-2 distances that determine selection/ordering.
__device__ __forceinline__ v2f pk_fma(v2f a, v2f b, v2f c) {
    v2f d; asm("v_pk_fma_f32 %0, %1, %2, %3" : "=v"(d) : "v"(a), "v"(b), "v"(c)); return d;
}
// Whole-wave shift lane i -> i+1 (DPP wave_shr:1, ctrl 0x138). Lane 0 keeps old.
__device__ __forceinline__ int dpp_shr1(int v) {
    return __builtin_amdgcn_update_dpp(v, v, 0x138, 0xf, 0xf, false);
}
// Per-lane select on an arbitrary 64-bit lane mask held in SGPRs: m ? t : f.
__device__ __forceinline__ int sel_mask_i(unsigned long long m, int t, int f) {
    int d; asm("v_cndmask_b32 %0, %2, %1, %3" : "=v"(d) : "v"(t), "v"(f), "s"(m));
    return d;
}

// ---------------------------------------------------------------------------
// Kernel 1: exact top-32 KNN + centered-xyz channels.
// R8: R7's staging was wrong because global_load_lds applies its imm offset
// to BOTH the global and LDS addresses. Fix: offset=0 always; staging is a
// pure linear byte copy (AoS global tile -> AoS LDS tile) with size=16.
// TILE=1024 pts (12 KB), ring-3 (36 KB LDS, 4 blocks/CU), counted vmcnt(3)
// keeps 2 tiles in flight across raw s_barriers (never drains in main loop).
// Compute pairs points (p, p+64): x's are 768 B apart -> ds_read2_b32,
// stride-3-dword lane pattern = 2 lanes/bank (conflict-free), pair lands in
// a VGPR pair for v_pk math. Pass-2 arithmetic / exact sorted insert /
// ascending candidate order are bit-identical to the verified R6 kernel.
// ---------------------------------------------------------------------------
constexpr int TILE = 1024;          // points per tile
constexpr int NT   = NPTS / TILE;   // 16 tiles per pass
constexpr int QPW  = 2;
constexpr int QPB  = 8;

#define VW3 asm volatile("s_waitcnt vmcnt(3)" ::: "memory")
#define VW0 asm volatile("s_waitcnt vmcnt(0)" ::: "memory")
#define BAR __builtin_amdgcn_s_barrier()

__global__ __launch_bounds__(256) void knn_kernel(
    const float* __restrict__ xyz,
    const float* __restrict__ new_xyz,
    int*   __restrict__ out_idx,
    float* __restrict__ out)
{
    // 3 ring buffers, raw AoS copy of a 1024-point tile (12288 B each).
    __shared__ __align__(16) float sb[3][TILE * 3];

    const int tid  = threadIdx.x;
    const int lane = tid & 63;
    const int wave = tid >> 6;
    const int b    = blockIdx.x >> 9;                  // 512 blocks per batch
    const int q0   = (blockIdx.x & 511) * QPB + wave * QPW;

    const float* xb = xyz + (size_t)b * NPTS * 3;
    // Per-lane global byte address for staging: wave w copies tile bytes
    // [w*3072, w*3072+3072) as 3 chunks of 64 lanes x 16 B.
    const char* gbase = (const char*)xb + wave * 3072 + lane * 16;

    // offset=0 ONLY: global addr entirely in per-lane gptr, LDS dst is
    // wave-uniform base (+ HW lane*16). No imm-offset ambiguity possible.
    auto STAGE = [&](int buf, int t0) {
        const char* g = gbase + (size_t)t0 * 12;
        char* l = (char*)(&sb[buf][0]) + wave * 3072;
#define GLL(k) __builtin_amdgcn_global_load_lds( \
        (const __attribute__((address_space(1))) unsigned int*)(g + (k) * 1024), \
        (__attribute__((address_space(3))) unsigned int*)(l + (k) * 1024), \
        16, 0, 0)
        GLL(0); GLL(1); GLL(2);
#undef GLL
    };

    // Negated query coords (wave-uniform -> SGPR) + packed VGPR broadcasts.
    float nqx[QPW], nqy[QPW], nqz[QPW];
    v2f nqx2[QPW], nqy2[QPW], nqz2[QPW];
#pragma unroll
    for (int j = 0; j < QPW; ++j) {
        const int base = ((b * NQ) + q0 + j) * 3;
        nqx[j] = __int_as_float(__builtin_amdgcn_readfirstlane(__float_as_int(-new_xyz[base + 0])));
        nqy[j] = __int_as_float(__builtin_amdgcn_readfirstlane(__float_as_int(-new_xyz[base + 1])));
        nqz[j] = __int_as_float(__builtin_amdgcn_readfirstlane(__float_as_int(-new_xyz[base + 2])));
        nqx2[j] = (v2f){nqx[j], nqx[j]};
        nqy2[j] = (v2f){nqy[j], nqy[j]};
        nqz2[j] = (v2f){nqz[j], nqz[j]};
    }

    const float INF  = __int_as_float(0x7f800000);
    const float NINF = __int_as_float(0xff800000);

    // ---------------- Pass 1: per-lane running minima (FMA ok) --------------
    float vmA[QPW], vmB[QPW];
#pragma unroll
    for (int j = 0; j < QPW; ++j) { vmA[j] = INF; vmB[j] = INF; }

    STAGE(0, 0);
    STAGE(1, TILE);
    VW3; BAR;                       // own tile-0 writes done + all waves' too
    {
        int cur = 0, pre = 2;
        for (int t = 0; t < NT; ++t) {
            if (t + 2 < NT) STAGE(pre, (t + 2) * TILE);
            const float* sp = &sb[cur][0];
#pragma unroll
            for (int ii = 0; ii < TILE / 128; ++ii) {
                // lane handles points (ii*128+lane, ii*128+lane+64)
                const float* qp = sp + 3 * (ii * 128 + lane);
                const v2f px2 = {qp[0], qp[192]};   // ds_read2_b32 pairs
                const v2f py2 = {qp[1], qp[193]};
                const v2f pz2 = {qp[2], qp[194]};
#pragma unroll
                for (int j = 0; j < QPW; ++j) {
                    const v2f dx = pk_add(px2, nqx2[j]);
                    const v2f dy = pk_add(py2, nqy2[j]);
                    const v2f dz = pk_add(pz2, nqz2[j]);
                    const v2f d2 = pk_fma(dx, dx, pk_fma(dy, dy, pk_mul(dz, dz)));
                    vmA[j] = fminf(vmA[j], d2.x);
                    vmB[j] = fminf(vmB[j], d2.y);
                }
            }
            if (t + 1 < NT) {
                if (t + 2 < NT) { VW3; } else { VW0; }
                BAR;                // tile t+1 visible to all waves
            }
            cur = (cur == 2) ? 0 : cur + 1;
            pre = (pre == 2) ? 0 : pre + 1;
        }
    }
    BAR;   // all waves done reading sb before pass-2 prologue overwrites it

    // Pass-2 prologue staging issued NOW so it overlaps the radix descent.
    STAGE(0, 0);
    STAGE(1, TILE);

    // ---------------- T' = exact 32nd smallest of 64 lane minima -----------
    // Lane minima used FMA; +64 ulps keeps T' a provable upper bound on the
    // exact-rn 32nd distance (rel. slack 3.8e-6 >> fma-vs-rn few-ulp error).
    float Tf[QPW];
#pragma unroll
    for (int j = 0; j < QPW; ++j) {
        const unsigned u = __float_as_uint(fminf(vmA[j], vmB[j]));
        unsigned t = 0x7fffffffu;                       // > all finite bits
        for (int bb = 30; bb >= 0; --bb) {              // uniform radix descent
            const unsigned tt = t ^ (1u << bb);
            const int cnt = __popcll(__ballot(u <= tt));
            if (cnt >= 32) t = tt;                      // s_cselect, branchless
        }
        Tf[j] = __uint_as_float(t + 64);
    }

    // ---------------- Pass 2: filtered exact selection (rn-exact) ----------
    float ld[QPW]; int li[QPW];
#pragma unroll
    for (int j = 0; j < QPW; ++j) {
        ld[j] = (lane < K) ? INF : NINF;   // -inf sentinel: lanes 32+ never shift
        li[j] = 0;
    }

    VW3; BAR;                       // pass-2 tile 0 landed
    {
        int cur = 0, pre = 2;
        for (int t = 0; t < NT; ++t) {
            if (t + 2 < NT) STAGE(pre, (t + 2) * TILE);
            const int t0 = t * TILE;
            const float* sp = &sb[cur][0];
#pragma unroll
            for (int ii = 0; ii < TILE / 128; ++ii) {
                const int gb = t0 + ii * 128;              // wave-uniform
                const float* qp = sp + 3 * (ii * 128 + lane);
                const v2f px2 = {qp[0], qp[192]};
                const v2f py2 = {qp[1], qp[193]};
                const v2f pz2 = {qp[2], qp[194]};
#pragma unroll
                for (int j = 0; j < QPW; ++j) {
                    const v2f dx = pk_add(px2, nqx2[j]);
                    const v2f dy = pk_add(py2, nqy2[j]);
                    const v2f dz = pk_add(pz2, nqz2[j]);
                    const v2f d2 = pk_add(pk_add(pk_mul(dx, dx), pk_mul(dy, dy)),
                                          pk_mul(dz, dz));
                    unsigned long long m0 = __ballot(d2.x <= Tf[j]);
                    unsigned long long m1 = __ballot(d2.y <= Tf[j]);
                    // all m0 candidates (gb+c) < all m1 candidates (gb+64+c):
                    // popping m0 to exhaustion first keeps global ascending order.
                    while (m0 | m1) {
                        const bool lo = (m0 != 0);
                        const unsigned long long mm = lo ? m0 : m1;
                        const int c = (int)__builtin_ctzll(mm);
                        if (lo) m0 &= m0 - 1; else m1 &= m1 - 1;
                        const int b0 = __builtin_amdgcn_readlane(__float_as_int(d2.x), c);
                        const int b1 = __builtin_amdgcn_readlane(__float_as_int(d2.y), c);
                        const float dn = __int_as_float(lo ? b0 : b1);
                        const int cand = gb + (lo ? 0 : 64) + c;
                        // Self-guarding sorted insert (no-op if dn >= current max).
                        const unsigned long long sh = __ballot(ld[j] > dn);
                        const int p = sh ? (int)__builtin_ctzll(sh) : 64;
                        const int sld = dpp_shr1(__float_as_int(ld[j]));
                        const int sli = dpp_shr1(li[j]);
                        const int nld = sel_mask_i(sh, sld, __float_as_int(ld[j]));
                        const int nli = sel_mask_i(sh, sli, li[j]);
                        ld[j] = __int_as_float((lane == p) ? __float_as_int(dn) : nld);
                        li[j] = (lane == p) ? cand : nli;
                    }
                }
            }
            if (t + 1 < NT) {
                if (t + 2 < NT) { VW3; } else { VW0; }
                BAR;
            }
            cur = (cur == 2) ? 0 : cur + 1;
            pre = (pre == 2) ? 0 : pre + 1;
        }
    }

    // Epilogue: write idx + centered xyz channels (0..2).
#pragma unroll
    for (int j = 0; j < QPW; ++j) {
        if (lane < K) {
            const int q   = q0 + j;
            const int idx = li[j];
            out_idx[((size_t)(b * NQ) + q) * K + lane] = idx;
            const float px = xb[idx * 3 + 0];
            const float py = xb[idx * 3 + 1];
            const float pz = xb[idx * 3 + 2];
            const size_t plane = (size_t)NQ * K;
            const size_t o = (((size_t)b * CHOUT + 0) * NQ + q) * K + lane;
            out[o]             = __fadd_rn(px, nqx[j]);   // == px - qx, exact
            out[o + plane]     = __fadd_rn(py, nqy[j]);
            out[o + 2 * plane] = __fadd_rn(pz, nqz[j]);
        }
    }
}

// ---------------------------------------------------------------------------
// Kernel T: features (B,C,N) -> featT (B,N,C), tiled via LDS, conflict-free.
// grid = B * N/128 = 512 blocks x 256 threads. ~34 MB traffic -> ~10 us.
// ---------------------------------------------------------------------------
__global__ __launch_bounds__(256) void transpose_kernel(
    const float* __restrict__ f, float* __restrict__ ft)
{
    __shared__ float sm[128][65];   // 33.3 KB, 65-stride: bank = (n + c) % 32
    const int tid = threadIdx.x;
    const int nb  = blockIdx.x & (NPTS / 128 - 1);
    const int b   = blockIdx.x >> 7;
    const int n0  = nb * 128;
    const float* fb = f + (size_t)b * NCH * NPTS;
    const int nn = tid & 127, chh = tid >> 7;
#pragma unroll
    for (int c = 0; c < NCH; c += 2)
        sm[nn][c + chh] = fb[(size_t)(c + chh) * NPTS + n0 + nn];
    __syncthreads();
    float* ftb = ft + ((size_t)b * NPTS + n0) * NCH;
#pragma unroll
    for (int g = 0; g < 32; ++g) {
        const int o = g * 256 + tid;            // linear over 128 n x 64 c
        ftb[o] = sm[o >> 6][o & 63];            // coalesced store, 2-way LDS read
    }
}

// ---------------------------------------------------------------------------
// Kernel G2: slot-major gather. Block = 256 threads handles 128 (q,k) slots
// (4 queries). idx read ONCE per slot (was 64x). Each thread pair pulls one
// point's 64 channels as 8 independent v4f loads (8-deep MLP, full-line use),
// transposes via LDS (<=2-way conflicts), stores channel-major coalesced.
// grid = B * NQ/4 = 4096 blocks; 33 KB LDS -> 4 blocks/CU, 16 waves/CU.
// ---------------------------------------------------------------------------
__global__ __launch_bounds__(256) void gather2_kernel(
    const float* __restrict__ ft,
    const int*   __restrict__ idx,
    float* __restrict__ out)
{
    __shared__ float smc[NCH][129];   // [c][slot], stride 129: bank = (c+s)%32

    const int tid = threadIdx.x;
    const int qt  = blockIdx.x & (NQ / 4 - 1);
    const int b   = blockIdx.x >> 10;                  // NQ/4 = 1024
    const size_t slot0 = ((size_t)b * NQ + (size_t)qt * 4) * K;   // 128 slots

    // phase 1: gather rows. thread pair (s, h): half h of slot s's channels.
    const int s = tid >> 1;
    const int h = tid & 1;
    const int p = idx[slot0 + s];
    const v4f* src = (const v4f*)(ft + ((size_t)b * NPTS + p) * NCH) + h * 8;
    v4f r[8];
#pragma unroll
    for (int k = 0; k < 8; ++k) r[k] = src[k];
#pragma unroll
    for (int k = 0; k < 8; ++k) {
        const int c0 = h * 32 + k * 4;
        smc[c0 + 0][s] = r[k].x;
        smc[c0 + 1][s] = r[k].y;
        smc[c0 + 2][s] = r[k].z;
        smc[c0 + 3][s] = r[k].w;
    }
    __syncthreads();

    // phase 2: channel-major coalesced stores. wave w: channels w, w+4, ...
    const int w = tid >> 6, l = tid & 63;
    const size_t plane = (size_t)NQ * K;
    float* ob = out + ((size_t)b * CHOUT + 3) * plane + (size_t)qt * (4 * K);
#pragma unroll
    for (int c = w; c < NCH; c += 4) {
        float* orow = ob + (size_t)c * plane;
        orow[l]      = smc[c][l];
        orow[64 + l] = smc[c][64 + l];
    }
}

// ---------------------------------------------------------------------------
// Fallback gather (R6 path) in case ws_size cannot hold featT.
// ---------------------------------------------------------------------------
__global__ __launch_bounds__(1024) void gather_kernel(
    const float* __restrict__ features,
    const int*   __restrict__ idx,
    float* __restrict__ out)
{
    __shared__ __align__(16) float row[NPTS];   // 64 KB

    const int tid  = threadIdx.x;
    const int half = blockIdx.x & 1;
    const int c    = (blockIdx.x >> 1) & 63;
    const int b    = blockIdx.x >> 7;

    const v4f* src = (const v4f*)(features + ((size_t)(b * NCH + c)) * NPTS);
    for (int k2 = tid; k2 < NPTS / 4; k2 += 1024) ((v4f*)row)[k2] = src[k2];
    __syncthreads();

    const size_t hofs = (size_t)half * (NQ * K / 2);
    const v4i* gi = (const v4i*)(idx + (size_t)b * NQ * K + hofs);
    v4f* dst = (v4f*)(out + ((size_t)(b * CHOUT + 3 + c)) * NQ * K + hofs);

    v4i cur = gi[tid];
#pragma unroll
    for (int it = 0; it < 16; ++it) {                  // NQ*K/8/1024 = 16
        v4i nxt;
        if (it < 15) nxt = gi[tid + (it + 1) * 1024];
        v4f o;
        o.x = row[cur.x]; o.y = row[cur.y]; o.z = row[cur.z]; o.w = row[cur.w];
        dst[tid + it * 1024] = o;
        cur = nxt;
    }
}

extern "C" void kernel_launch(void* const* d_in, const int* in_sizes, int n_in,
                              void* d_out, int out_size, void* d_ws, size_t ws_size,
                              hipStream_t stream) {
    const float* xyz      = (const float*)d_in[0];
    const float* new_xyz  = (const float*)d_in[1];
    const float* features = (const float*)d_in[2];
    float* out    = (float*)d_out;
    int*   ws_idx = (int*)d_ws;   // 4*4096*32*4 = 2 MB scratch

    const size_t idx_bytes = (size_t)NBATCH * NQ * K * sizeof(int);        // 2 MB
    const size_t ft_bytes  = (size_t)NBATCH * NPTS * NCH * sizeof(float);  // 16.8 MB
    float* featT = (float*)((char*)d_ws + idx_bytes);

    if (ws_size >= idx_bytes + ft_bytes) {
        transpose_kernel<<<dim3(NBATCH * (NPTS / 128)), dim3(256), 0, stream>>>(features, featT);
        knn_kernel<<<dim3(NBATCH * (NQ / QPB)), dim3(256), 0, stream>>>(xyz, new_xyz, ws_idx, out);
        gather2_kernel<<<dim3(NBATCH * (NQ / 4)), dim3(256), 0, stream>>>(featT, ws_idx, out);
    } else {
        knn_kernel<<<dim3(NBATCH * (NQ / QPB)), dim3(256), 0, stream>>>(xyz, new_xyz, ws_idx, out);
        gather_kernel<<<dim3(NBATCH * NCH * 2), dim3(1024), 0, stream>>>(features, ws_idx, out);
    }
}

// Round 3
// 291.463 us; speedup vs baseline: 1.1601x; 1.1601x over previous
//
#include <hip/hip_runtime.h>

#define NBATCH 4
#define NPTS   16384
#define NQ     4096
#define NCH    64
#define K      32
#define CHOUT  67   // 3 + NCH

typedef float v2f __attribute__((ext_vector_type(2)));
typedef float v4f __attribute__((ext_vector_type(4)));
typedef int   v4i __attribute__((ext_vector_type(4)));

// Packed fp32 ops via asm: exact rn rounding, no contraction possible.
__device__ __forceinline__ v2f pk_add(v2f a, v2f b) {
    v2f d; asm("v_pk_add_f32 %0, %1, %2" : "=v"(d) : "v"(a), "v"(b)); return d;
}
__device__ __forceinline__ v2f pk_mul(v2f a, v2f b) {
    v2f d; asm("v_pk_mul_f32 %0, %1, %2" : "=v"(d) : "v"(a), "v"(b)); return d;
}
// FMA variant: used ONLY in pass 1 (threshold estimate), never for the exact
// pass-2 distances that determine selection/ordering.
__device__ __forceinline__ v2f pk_fma(v2f a, v2f b, v2f c) {
    v2f d; asm("v_pk_fma_f32 %0, %1, %2, %3" : "=v"(d) : "v"(a), "v"(b), "v"(c)); return d;
}
// Whole-wave shift lane i -> i+1 (DPP wave_shr:1, ctrl 0x138). Lane 0 keeps old.
__device__ __forceinline__ int dpp_shr1(int v) {
    return __builtin_amdgcn_update_dpp(v, v, 0x138, 0xf, 0xf, false);
}
// Per-lane select on an arbitrary 64-bit lane mask held in SGPRs: m ? t : f.
__device__ __forceinline__ int sel_mask_i(unsigned long long m, int t, int f) {
    int d; asm("v_cndmask_b32 %0, %2, %1, %3" : "=v"(d) : "v"(t), "v"(f), "s"(m));
    return d;
}

// ---------------------------------------------------------------------------
// R9 theory: the knn kernel is LDS-READ-PIPE bound (per-CU, shared by 4
// SIMDs): 197 KB LDS reads/wave/pass x 32 waves/CU x 2 passes ~= 119 us at
// measured ds_read efficiency -- which is why R6 (b64 SoA) == R8 (read2 AoS)
// and why occupancy 64%->38% changed nothing. Fixes:
//   QPW 2->4: each LDS point read now feeds 4 queries -> per-CU LDS cycles
//   halve (16 waves/CU). VALU total unchanged.
//   FUSED gather epilogue: wave already holds its queries' indices ->
//   gather features from featT (B,N,C) directly, full-cache-line reads,
//   per-channel chunked stores. Deletes the separate 145-us gather kernel
//   and the idx round-trip.
// Staging/selection logic is bit-identical to the verified R8 kernel.
// ---------------------------------------------------------------------------
constexpr int TILE = 1024;          // points per tile
constexpr int NT   = NPTS / TILE;   // 16 tiles per pass
constexpr int QPW  = 4;
constexpr int QPB  = 16;            // 4 waves x QPW

#define VW3 asm volatile("s_waitcnt vmcnt(3)" ::: "memory")
#define VW0 asm volatile("s_waitcnt vmcnt(0)" ::: "memory")
#define BAR __builtin_amdgcn_s_barrier()

template <bool FUSED>
__global__ __launch_bounds__(256) void knn_kernel(
    const float* __restrict__ xyz,
    const float* __restrict__ new_xyz,
    const float* __restrict__ ft,     // featT (B,N,C); used when FUSED
    int*   __restrict__ out_idx,      // used when !FUSED
    float* __restrict__ out)
{
    // 3 ring buffers, raw AoS copy of a 1024-point tile (12288 B each).
    __shared__ __align__(16) float sb[3][TILE * 3];

    const int tid  = threadIdx.x;
    const int lane = tid & 63;
    const int wave = tid >> 6;
    const int b    = blockIdx.x >> 8;                  // 256 blocks per batch
    const int q0   = (blockIdx.x & 255) * QPB + wave * QPW;

    const float* xb = xyz + (size_t)b * NPTS * 3;
    // Per-lane global byte address for staging: wave w copies tile bytes
    // [w*3072, w*3072+3072) as 3 chunks of 64 lanes x 16 B.
    const char* gbase = (const char*)xb + wave * 3072 + lane * 16;

    // offset=0 ONLY (global_load_lds applies imm offset to BOTH addresses).
    auto STAGE = [&](int buf, int t0) {
        const char* g = gbase + (size_t)t0 * 12;
        char* l = (char*)(&sb[buf][0]) + wave * 3072;
#define GLL(k) __builtin_amdgcn_global_load_lds( \
        (const __attribute__((address_space(1))) unsigned int*)(g + (k) * 1024), \
        (__attribute__((address_space(3))) unsigned int*)(l + (k) * 1024), \
        16, 0, 0)
        GLL(0); GLL(1); GLL(2);
#undef GLL
    };

    // Negated query coords (wave-uniform -> SGPR) + packed VGPR broadcasts.
    float nqx[QPW], nqy[QPW], nqz[QPW];
    v2f nqx2[QPW], nqy2[QPW], nqz2[QPW];
#pragma unroll
    for (int j = 0; j < QPW; ++j) {
        const int base = ((b * NQ) + q0 + j) * 3;
        nqx[j] = __int_as_float(__builtin_amdgcn_readfirstlane(__float_as_int(-new_xyz[base + 0])));
        nqy[j] = __int_as_float(__builtin_amdgcn_readfirstlane(__float_as_int(-new_xyz[base + 1])));
        nqz[j] = __int_as_float(__builtin_amdgcn_readfirstlane(__float_as_int(-new_xyz[base + 2])));
        nqx2[j] = (v2f){nqx[j], nqx[j]};
        nqy2[j] = (v2f){nqy[j], nqy[j]};
        nqz2[j] = (v2f){nqz[j], nqz[j]};
    }

    const float INF  = __int_as_float(0x7f800000);
    const float NINF = __int_as_float(0xff800000);

    // ---------------- Pass 1: per-lane running minima (FMA ok) --------------
    float vmA[QPW], vmB[QPW];
#pragma unroll
    for (int j = 0; j < QPW; ++j) { vmA[j] = INF; vmB[j] = INF; }

    STAGE(0, 0);
    STAGE(1, TILE);
    VW3; BAR;                       // own tile-0 writes done + all waves' too
    {
        int cur = 0, pre = 2;
        for (int t = 0; t < NT; ++t) {
            if (t + 2 < NT) STAGE(pre, (t + 2) * TILE);
            const float* sp = &sb[cur][0];
#pragma unroll
            for (int ii = 0; ii < TILE / 128; ++ii) {
                // lane handles points (ii*128+lane, ii*128+lane+64)
                const float* qp = sp + 3 * (ii * 128 + lane);
                const v2f px2 = {qp[0], qp[192]};   // ds_read2_b32 pairs
                const v2f py2 = {qp[1], qp[193]};
                const v2f pz2 = {qp[2], qp[194]};
#pragma unroll
                for (int j = 0; j < QPW; ++j) {
                    const v2f dx = pk_add(px2, nqx2[j]);
                    const v2f dy = pk_add(py2, nqy2[j]);
                    const v2f dz = pk_add(pz2, nqz2[j]);
                    const v2f d2 = pk_fma(dx, dx, pk_fma(dy, dy, pk_mul(dz, dz)));
                    vmA[j] = fminf(vmA[j], d2.x);
                    vmB[j] = fminf(vmB[j], d2.y);
                }
            }
            if (t + 1 < NT) {
                if (t + 2 < NT) { VW3; } else { VW0; }
                BAR;                // tile t+1 visible to all waves
            }
            cur = (cur == 2) ? 0 : cur + 1;
            pre = (pre == 2) ? 0 : pre + 1;
        }
    }
    BAR;   // all waves done reading sb before pass-2 prologue overwrites it

    // Pass-2 prologue staging issued NOW so it overlaps the radix descent.
    STAGE(0, 0);
    STAGE(1, TILE);

    // ---------------- T' = exact 32nd smallest of 64 lane minima -----------
    // Lane minima used FMA; +64 ulps keeps T' a provable upper bound on the
    // exact-rn 32nd distance (rel. slack 3.8e-6 >> fma-vs-rn few-ulp error).
    float Tf[QPW];
#pragma unroll
    for (int j = 0; j < QPW; ++j) {
        const unsigned u = __float_as_uint(fminf(vmA[j], vmB[j]));
        unsigned t = 0x7fffffffu;                       // > all finite bits
        for (int bb = 30; bb >= 0; --bb) {              // uniform radix descent
            const unsigned tt = t ^ (1u << bb);
            const int cnt = __popcll(__ballot(u <= tt));
            if (cnt >= 32) t = tt;                      // s_cselect, branchless
        }
        Tf[j] = __uint_as_float(t + 64);
    }

    // ---------------- Pass 2: filtered exact selection (rn-exact) ----------
    float ld[QPW]; int li[QPW];
#pragma unroll
    for (int j = 0; j < QPW; ++j) {
        ld[j] = (lane < K) ? INF : NINF;   // -inf sentinel: lanes 32+ never shift
        li[j] = 0;
    }

    VW3; BAR;                       // pass-2 tile 0 landed
    {
        int cur = 0, pre = 2;
        for (int t = 0; t < NT; ++t) {
            if (t + 2 < NT) STAGE(pre, (t + 2) * TILE);
            const int t0 = t * TILE;
            const float* sp = &sb[cur][0];
#pragma unroll
            for (int ii = 0; ii < TILE / 128; ++ii) {
                const int gb = t0 + ii * 128;              // wave-uniform
                const float* qp = sp + 3 * (ii * 128 + lane);
                const v2f px2 = {qp[0], qp[192]};
                const v2f py2 = {qp[1], qp[193]};
                const v2f pz2 = {qp[2], qp[194]};
#pragma unroll
                for (int j = 0; j < QPW; ++j) {
                    const v2f dx = pk_add(px2, nqx2[j]);
                    const v2f dy = pk_add(py2, nqy2[j]);
                    const v2f dz = pk_add(pz2, nqz2[j]);
                    const v2f d2 = pk_add(pk_add(pk_mul(dx, dx), pk_mul(dy, dy)),
                                          pk_mul(dz, dz));
                    unsigned long long m0 = __ballot(d2.x <= Tf[j]);
                    unsigned long long m1 = __ballot(d2.y <= Tf[j]);
                    // all m0 candidates (gb+c) < all m1 candidates (gb+64+c):
                    // popping m0 to exhaustion first keeps global ascending order.
                    while (m0 | m1) {
                        const bool lo = (m0 != 0);
                        const unsigned long long mm = lo ? m0 : m1;
                        const int c = (int)__builtin_ctzll(mm);
                        if (lo) m0 &= m0 - 1; else m1 &= m1 - 1;
                        const int b0 = __builtin_amdgcn_readlane(__float_as_int(d2.x), c);
                        const int b1 = __builtin_amdgcn_readlane(__float_as_int(d2.y), c);
                        const float dn = __int_as_float(lo ? b0 : b1);
                        const int cand = gb + (lo ? 0 : 64) + c;
                        // Self-guarding sorted insert (no-op if dn >= current max).
                        const unsigned long long sh = __ballot(ld[j] > dn);
                        const int p = sh ? (int)__builtin_ctzll(sh) : 64;
                        const int sld = dpp_shr1(__float_as_int(ld[j]));
                        const int sli = dpp_shr1(li[j]);
                        const int nld = sel_mask_i(sh, sld, __float_as_int(ld[j]));
                        const int nli = sel_mask_i(sh, sli, li[j]);
                        ld[j] = __int_as_float((lane == p) ? __float_as_int(dn) : nld);
                        li[j] = (lane == p) ? cand : nli;
                    }
                }
            }
            if (t + 1 < NT) {
                if (t + 2 < NT) { VW3; } else { VW0; }
                BAR;
            }
            cur = (cur == 2) ? 0 : cur + 1;
            pre = (pre == 2) ? 0 : pre + 1;
        }
    }

    // ---------------- Epilogue ----------------
    const size_t plane = (size_t)NQ * K;
#pragma unroll
    for (int j = 0; j < QPW; ++j) {
        const int q = q0 + j;
        // centered xyz channels 0..2 (exact: px + (-qx), rn)
        if (lane < K) {
            const int idx = li[j];
            const float px = xb[idx * 3 + 0];
            const float py = xb[idx * 3 + 1];
            const float pz = xb[idx * 3 + 2];
            const size_t o = (((size_t)b * CHOUT + 0) * NQ + q) * K + lane;
            out[o]             = __fadd_rn(px, nqx[j]);
            out[o + plane]     = __fadd_rn(py, nqy[j]);
            out[o + 2 * plane] = __fadd_rn(pz, nqz[j]);
        }
        if (FUSED) {
            // feature channels 3..66: lane (s,h) pulls half-row h (128 B,
            // one full cache line) of point li[j]@lane s, scatters per-channel.
            const int s = lane & 31, h = lane >> 5;
            const int pidx = __shfl(li[j], s);
            const v4f* src = (const v4f*)(ft + ((size_t)b * NPTS + pidx) * NCH) + h * 8;
            v4f r[8];
#pragma unroll
            for (int k2 = 0; k2 < 8; ++k2) r[k2] = src[k2];
            float* ob = out + (((size_t)b * CHOUT + 3) * NQ + q) * K + s;
#pragma unroll
            for (int k2 = 0; k2 < 8; ++k2) {
                const int c0 = h * 32 + k2 * 4;
                ob[(size_t)(c0 + 0) * plane] = r[k2].x;
                ob[(size_t)(c0 + 1) * plane] = r[k2].y;
                ob[(size_t)(c0 + 2) * plane] = r[k2].z;
                ob[(size_t)(c0 + 3) * plane] = r[k2].w;
            }
        } else if (lane < K) {
            out_idx[((size_t)(b * NQ) + q) * K + lane] = li[j];
        }
    }
}

// ---------------------------------------------------------------------------
// Kernel T: features (B,C,N) -> featT (B,N,C), tiled via LDS, conflict-free.
// grid = B * N/128 = 512 blocks x 256 threads. ~34 MB traffic -> ~10 us.
// ---------------------------------------------------------------------------
__global__ __launch_bounds__(256) void transpose_kernel(
    const float* __restrict__ f, float* __restrict__ ft)
{
    __shared__ float sm[128][65];   // 33.3 KB, 65-stride: bank = (n + c) % 32
    const int tid = threadIdx.x;
    const int nb  = blockIdx.x & (NPTS / 128 - 1);
    const int b   = blockIdx.x >> 7;
    const int n0  = nb * 128;
    const float* fb = f + (size_t)b * NCH * NPTS;
    const int nn = tid & 127, chh = tid >> 7;
#pragma unroll
    for (int c = 0; c < NCH; c += 2)
        sm[nn][c + chh] = fb[(size_t)(c + chh) * NPTS + n0 + nn];
    __syncthreads();
    float* ftb = ft + ((size_t)b * NPTS + n0) * NCH;
#pragma unroll
    for (int g = 0; g < 32; ++g) {
        const int o = g * 256 + tid;            // linear over 128 n x 64 c
        ftb[o] = sm[o >> 6][o & 63];            // coalesced store, 2-way LDS read
    }
}

// ---------------------------------------------------------------------------
// Fallback gather (R6 path) in case ws_size cannot hold featT.
// ---------------------------------------------------------------------------
__global__ __launch_bounds__(1024) void gather_kernel(
    const float* __restrict__ features,
    const int*   __restrict__ idx,
    float* __restrict__ out)
{
    __shared__ __align__(16) float row[NPTS];   // 64 KB

    const int tid  = threadIdx.x;
    const int half = blockIdx.x & 1;
    const int c    = (blockIdx.x >> 1) & 63;
    const int b    = blockIdx.x >> 7;

    const v4f* src = (const v4f*)(features + ((size_t)(b * NCH + c)) * NPTS);
    for (int k2 = tid; k2 < NPTS / 4; k2 += 1024) ((v4f*)row)[k2] = src[k2];
    __syncthreads();

    const size_t hofs = (size_t)half * (NQ * K / 2);
    const v4i* gi = (const v4i*)(idx + (size_t)b * NQ * K + hofs);
    v4f* dst = (v4f*)(out + ((size_t)(b * CHOUT + 3 + c)) * NQ * K + hofs);

    v4i cur = gi[tid];
#pragma unroll
    for (int it = 0; it < 16; ++it) {                  // NQ*K/8/1024 = 16
        v4i nxt;
        if (it < 15) nxt = gi[tid + (it + 1) * 1024];
        v4f o;
        o.x = row[cur.x]; o.y = row[cur.y]; o.z = row[cur.z]; o.w = row[cur.w];
        dst[tid + it * 1024] = o;
        cur = nxt;
    }
}

extern "C" void kernel_launch(void* const* d_in, const int* in_sizes, int n_in,
                              void* d_out, int out_size, void* d_ws, size_t ws_size,
                              hipStream_t stream) {
    const float* xyz      = (const float*)d_in[0];
    const float* new_xyz  = (const float*)d_in[1];
    const float* features = (const float*)d_in[2];
    float* out = (float*)d_out;

    const size_t ft_bytes = (size_t)NBATCH * NPTS * NCH * sizeof(float);  // 16.8 MB

    if (ws_size >= ft_bytes) {
        float* featT = (float*)d_ws;
        transpose_kernel<<<dim3(NBATCH * (NPTS / 128)), dim3(256), 0, stream>>>(features, featT);
        knn_kernel<true><<<dim3(NBATCH * (NQ / QPB)), dim3(256), 0, stream>>>(
            xyz, new_xyz, featT, nullptr, out);
    } else {
        int* ws_idx = (int*)d_ws;   // 2 MB
        knn_kernel<false><<<dim3(NBATCH * (NQ / QPB)), dim3(256), 0, stream>>>(
            xyz, new_xyz, nullptr, ws_idx, out);
        gather_kernel<<<dim3(NBATCH * NCH * 2), dim3(1024), 0, stream>>>(features, ws_idx, out);
    }
}